// Round 21
// baseline (2964.161 us; speedup 1.0000x reference)
//
#include <hip/hip_runtime.h>

#define NR 512
#define NI 128
#define B 32
#define T 1000
// Locked numeric model (verified PASS rounds 13-20):
//  - input GEMM: per element single ascending-i FMA chain.
//  - z @ w_rec_masked: two 256-wide ascending-k chains (OpenBLAS K-panel
//    rebalancing: [0,256)+[256,512)), joined by one rounded add.
//    Binary z => only active rows; masked diag and zero-row pads are exact +0
//    (partial sums never produce -0, so fadd(s,+0)=s exactly, any position).
//  - elementwise: separate rounded f32 ops ((f32(decay)*v) + i_t) - z.
//  - pred: EMA over (b_out + spikes@w_out), f64, post-hoc in k_pred (loose tol).
// Round 21: VALU-issue-bound (R20: 71% VALUBusy on active CUs) -> cut issue
// volume + fixed costs: per-wave-segment lists (wave-local scatter/refresh,
// 2 barriers/step), straight-line chain (no selects/dual-buffer), SALU row
// addressing via readfirstlane-uniform row pointers, h=1 waves chain-only.

__device__ __forceinline__ float mul_nofma(float a, float b) {
    float r = a * b;
    asm volatile("" : "+v"(r));
    return r;
}

// LDS-only barrier: waits LDS ops, leaves global loads/stores in flight.
__device__ __forceinline__ void bar_lds() {
    asm volatile("s_waitcnt lgkmcnt(0)\n\ts_barrier" ::: "memory");
}

// ---------------- Kernel 0: masked w_rec copy + zero row into d_ws
__global__ __launch_bounds__(512) void k_prep(const float* __restrict__ w_rec,
                                              float* __restrict__ w_ws) {
    const int r = blockIdx.x, u = threadIdx.x;
    float val = 0.f;
    if (r < NR && r != u) val = w_rec[r * NR + u];
    w_ws[r * NR + u] = val;
}

// ---------------- Kernel 1: i_in = inputs @ w_in -> voltages region of d_out
template <int ROWS>
__global__ __launch_bounds__(512) void k_in_gemm(const float* __restrict__ inputs,
                                                 const float* __restrict__ w_in,
                                                 float* __restrict__ i_in) {
    const int u = threadIdx.x;
    const int r0 = blockIdx.x * ROWS;
    float acc[ROWS];
#pragma unroll
    for (int r = 0; r < ROWS; ++r) acc[r] = 0.f;
    const float* __restrict__ inp = inputs + (long)r0 * NI;
#pragma unroll 4
    for (int i = 0; i < NI; ++i) {
        float w = w_in[i * NR + u];
#pragma unroll
        for (int r = 0; r < ROWS; ++r)
            acc[r] = __builtin_fmaf(inp[r * NI + i], w, acc[r]);   // ascending i, FMA
    }
#pragma unroll
    for (int r = 0; r < ROWS; ++r)
        i_in[(long)(r0 + r) * NR + u] = acc[r];
}

// ---- 16-row chain block: uniform row pointers (SALU addr) + 16 chained adds
__device__ __forceinline__ void sum16(const int* __restrict__ sp,
                                      const float* __restrict__ w_ws, int u,
                                      float& s) {
    int4 ja = *(const int4*)(sp);
    int4 jb = *(const int4*)(sp + 4);
    int4 jc = *(const int4*)(sp + 8);
    int4 jd = *(const int4*)(sp + 12);
    const float* r0  = w_ws + (__builtin_amdgcn_readfirstlane(ja.x) << 9);
    const float* r1  = w_ws + (__builtin_amdgcn_readfirstlane(ja.y) << 9);
    const float* r2  = w_ws + (__builtin_amdgcn_readfirstlane(ja.z) << 9);
    const float* r3  = w_ws + (__builtin_amdgcn_readfirstlane(ja.w) << 9);
    const float* r4  = w_ws + (__builtin_amdgcn_readfirstlane(jb.x) << 9);
    const float* r5  = w_ws + (__builtin_amdgcn_readfirstlane(jb.y) << 9);
    const float* r6  = w_ws + (__builtin_amdgcn_readfirstlane(jb.z) << 9);
    const float* r7  = w_ws + (__builtin_amdgcn_readfirstlane(jb.w) << 9);
    const float* r8  = w_ws + (__builtin_amdgcn_readfirstlane(jc.x) << 9);
    const float* r9  = w_ws + (__builtin_amdgcn_readfirstlane(jc.y) << 9);
    const float* r10 = w_ws + (__builtin_amdgcn_readfirstlane(jc.z) << 9);
    const float* r11 = w_ws + (__builtin_amdgcn_readfirstlane(jc.w) << 9);
    const float* r12 = w_ws + (__builtin_amdgcn_readfirstlane(jd.x) << 9);
    const float* r13 = w_ws + (__builtin_amdgcn_readfirstlane(jd.y) << 9);
    const float* r14 = w_ws + (__builtin_amdgcn_readfirstlane(jd.z) << 9);
    const float* r15 = w_ws + (__builtin_amdgcn_readfirstlane(jd.w) << 9);
    float f0 = r0[u], f1 = r1[u], f2 = r2[u], f3 = r3[u];
    float f4 = r4[u], f5 = r5[u], f6 = r6[u], f7 = r7[u];
    float f8 = r8[u], f9 = r9[u], f10 = r10[u], f11 = r11[u];
    float f12 = r12[u], f13 = r13[u], f14 = r14[u], f15 = r15[u];
    s = __fadd_rn(s, f0);  s = __fadd_rn(s, f1);
    s = __fadd_rn(s, f2);  s = __fadd_rn(s, f3);
    s = __fadd_rn(s, f4);  s = __fadd_rn(s, f5);
    s = __fadd_rn(s, f6);  s = __fadd_rn(s, f7);
    s = __fadd_rn(s, f8);  s = __fadd_rn(s, f9);
    s = __fadd_rn(s, f10); s = __fadd_rn(s, f11);
    s = __fadd_rn(s, f12); s = __fadd_rn(s, f13);
    s = __fadd_rn(s, f14); s = __fadd_rn(s, f15);
}

// ---------------- Kernel 2: per-batch LIF scan, segment lists, 2 barriers/step.
// 32 blocks x 1024 threads: h = tid>>9 (panel), u = tid&511 (column).
// h=0 threads: ballot/scatter/update/stores + panel-A chain.
// h=1 threads: panel-B chain only.
__global__ __launch_bounds__(1024) void k_scan(const float* __restrict__ w_ws,
                                               float* __restrict__ out) {
    const int b = blockIdx.x;
    const int tid = threadIdx.x;
    const int u = tid & (NR - 1);
    const int h = tid >> 9;
    const int wav = tid >> 6;          // 0..15 ; h=0 waves are 0..7
    const int lane = tid & 63;

    float* __restrict__ volt_b = out + (long)b * (T * NR);                 // also i_in (in-place)
    float* __restrict__ spk_b  = out + (long)B * T * NR + (long)b * (T * NR);

    // Per-wave segments: panel A (rows j<256) = waves 0..3 -> listA[wav*64+..]
    //                    panel B (rows j>=256) = waves 4..7 -> listB[(wav-4)*64+..]
    __shared__ __align__(16) int listA[256];
    __shared__ __align__(16) int listB[256];
    __shared__ __align__(16) int wcnt8[8];
    __shared__ float shs1[NR];

    float v = 0.f, z = 0.f;            // live only in h=0
    const float decay = 0.951229424500714f;   // f32 rounding of the python scalar

    for (int t = 0; t < T; ++t) {
        float ii = 0.f;
        if (h == 0) {
            ii = volt_b[t * NR + u];   // prefetch; consumed after the chain

            // ---- wave-local ballot / scatter / tail-refresh / count publish
            unsigned long long m = __ballot(z > 0.5f);
            int myc = __popcll(m);
            int* seg = (wav < 4) ? (listA + wav * 64) : (listB + (wav - 4) * 64);
            if (z > 0.5f) {
                int below = __popcll(m & ((1ull << lane) - 1ull));
                seg[below] = u;                 // ascending u within segment
            }
            if (lane >= myc) seg[lane] = NR;    // pad/stale-refresh -> zero row
            if (lane == 0) wcnt8[wav] = myc;
        }
        bar_lds();                              // 1: lists + counts ready

        // ---- own-panel chain: 4 segments, ascending, padded to 16 (exact +0)
        float s = 0.f;
        {
            const int* lp = h ? listB : listA;
            int4 cq = *(const int4*)&wcnt8[h * 4];
#pragma unroll
            for (int w = 0; w < 4; ++w) {
                int c = (w == 0) ? cq.x : (w == 1) ? cq.y : (w == 2) ? cq.z : cq.w;
                int pc = (c + 15) & ~15;
                const int* sp = lp + w * 64;
                for (int k = 0; k < pc; k += 16)
                    sum16(sp + k, w_ws, u, s);
            }
        }
        if (h == 1) shs1[u] = s;
        bar_lds();                              // 2: h=1 partial ready

        // ---- join + LIF update + stores (h=0 only; reference op order)
        if (h == 0) {
            float rec = __fadd_rn(s, shs1[u]);  // panel join (one rounded add)
            float it = __fadd_rn(ii, rec);
            float m1 = mul_nofma(decay, v);
            float t2 = __fadd_rn(m1, it);
            float vn = __fsub_rn(t2, z);
            float zn = (vn > 1.0f) ? 1.0f : 0.0f;
            volt_b[t * NR + u] = vn;
            spk_b[t * NR + u]  = zn;
            v = vn; z = zn;
        }
    }
}

// ---------------- Kernel 3: pred = EMA(b_out + spikes @ w_out), post-hoc.
__global__ __launch_bounds__(512) void k_pred(const float* __restrict__ w_out,
                                              const float* __restrict__ b_out,
                                              float* __restrict__ out) {
    const int b = blockIdx.x;
    const int tid = threadIdx.x;
    const int wav = tid >> 6, lane = tid & 63;
    const float* __restrict__ spk_b = out + (long)B * T * NR + (long)b * (T * NR);
    float* __restrict__ pred = out + 2L * B * T * NR + (long)b * T;

    __shared__ double projs[T];   // 8 KB

    double wo[8];
#pragma unroll
    for (int q = 0; q < 8; ++q) wo[q] = (double)w_out[lane + q * 64];

    for (int t = wav; t < T; t += 8) {
        double p = 0.0;
#pragma unroll
        for (int q = 0; q < 8; ++q)
            p += (double)spk_b[t * NR + lane + q * 64] * wo[q];
#pragma unroll
        for (int o = 32; o > 0; o >>= 1) p += __shfl_xor(p, o, 64);
        if (lane == 0) projs[t] = p;
    }
    __syncthreads();
    if (tid == 0) {
        const double bo = (double)b_out[0];
        double ema = 0.0;
        for (int t = 0; t < T; ++t) {
            ema = 0.8 * ema + 0.2 * (bo + projs[t]);
            pred[t] = (float)ema;
        }
    }
}

// ---------------- Fallback: verified round-13 scan (no d_ws needed)
__global__ __launch_bounds__(512) void k_scan_ref(const float* __restrict__ w_rec,
                                                  const float* __restrict__ w_out,
                                                  const float* __restrict__ b_out,
                                                  float* __restrict__ out) {
    const int b = blockIdx.x;
    const int u = threadIdx.x;
    const int wav = u >> 6, lane = u & 63;
    const int KC = 256;

    float* __restrict__ volt_b = out + (long)b * (T * NR);
    float* __restrict__ spk_b  = out + (long)B * T * NR + (long)b * (T * NR);
    float* __restrict__ pred   = out + 2L * B * T * NR;

    __shared__ __align__(16) int list[NR];
    __shared__ int wcnt[8];
    __shared__ double projp[8];

    float v = 0.f, z = 0.f;
    const float decay = 0.951229424500714f;
    const double wo = (double)w_out[u];
    const double bo = (double)b_out[0];
    double ema = 0.0;

    for (int t = 0; t < T; ++t) {
        unsigned long long m = __ballot(z > 0.5f);
        if (lane == 0) wcnt[wav] = __popcll(m);
        __syncthreads();
        int cnt = 0, base = 0;
#pragma unroll
        for (int w2 = 0; w2 < 8; ++w2) {
            int c = wcnt[w2];
            if (w2 < wav) base += c;
            cnt += c;
        }
        if (z > 0.5f) {
            int pos = base + __popcll(m & ((1ull << lane) - 1ull));
            list[pos] = u;
        }
        float ii = volt_b[t * NR + u];
        __syncthreads();

        float s1 = 0.f, s2 = 0.f;
        int k = 0;
        for (; k + 8 <= cnt; k += 8) {
            int4 ja = *(const int4*)&list[k];
            int4 jb = *(const int4*)&list[k + 4];
            int j0 = __builtin_amdgcn_readfirstlane(ja.x);
            int j1 = __builtin_amdgcn_readfirstlane(ja.y);
            int j2 = __builtin_amdgcn_readfirstlane(ja.z);
            int j3 = __builtin_amdgcn_readfirstlane(ja.w);
            int j4 = __builtin_amdgcn_readfirstlane(jb.x);
            int j5 = __builtin_amdgcn_readfirstlane(jb.y);
            int j6 = __builtin_amdgcn_readfirstlane(jb.z);
            int j7 = __builtin_amdgcn_readfirstlane(jb.w);
            float w0 = w_rec[j0 * NR + u]; if (j0 == u) w0 = 0.f;
            float w1 = w_rec[j1 * NR + u]; if (j1 == u) w1 = 0.f;
            float w2 = w_rec[j2 * NR + u]; if (j2 == u) w2 = 0.f;
            float w3 = w_rec[j3 * NR + u]; if (j3 == u) w3 = 0.f;
            float w4 = w_rec[j4 * NR + u]; if (j4 == u) w4 = 0.f;
            float w5 = w_rec[j5 * NR + u]; if (j5 == u) w5 = 0.f;
            float w6 = w_rec[j6 * NR + u]; if (j6 == u) w6 = 0.f;
            float w7 = w_rec[j7 * NR + u]; if (j7 == u) w7 = 0.f;
            if (j0 < KC) s1 = __fadd_rn(s1, w0); else s2 = __fadd_rn(s2, w0);
            if (j1 < KC) s1 = __fadd_rn(s1, w1); else s2 = __fadd_rn(s2, w1);
            if (j2 < KC) s1 = __fadd_rn(s1, w2); else s2 = __fadd_rn(s2, w2);
            if (j3 < KC) s1 = __fadd_rn(s1, w3); else s2 = __fadd_rn(s2, w3);
            if (j4 < KC) s1 = __fadd_rn(s1, w4); else s2 = __fadd_rn(s2, w4);
            if (j5 < KC) s1 = __fadd_rn(s1, w5); else s2 = __fadd_rn(s2, w5);
            if (j6 < KC) s1 = __fadd_rn(s1, w6); else s2 = __fadd_rn(s2, w6);
            if (j7 < KC) s1 = __fadd_rn(s1, w7); else s2 = __fadd_rn(s2, w7);
        }
        for (; k < cnt; ++k) {
            int j = __builtin_amdgcn_readfirstlane(list[k]);
            float w = w_rec[j * NR + u];
            if (j == u) w = 0.f;
            if (j < KC) s1 = __fadd_rn(s1, w); else s2 = __fadd_rn(s2, w);
        }
        float rec = __fadd_rn(s1, s2);

        float it = __fadd_rn(ii, rec);
        float m1 = mul_nofma(decay, v);
        float t2 = __fadd_rn(m1, it);
        float vn = __fsub_rn(t2, z);
        float zn = (vn > 1.0f) ? 1.0f : 0.0f;
        volt_b[t * NR + u] = vn;
        spk_b[t * NR + u]  = zn;

        double p = (double)zn * wo;
#pragma unroll
        for (int o = 32; o > 0; o >>= 1) p += __shfl_xor(p, o, 64);
        if (lane == 0) projp[wav] = p;
        __syncthreads();
        if (u == 0) {
            double pr = bo;
#pragma unroll
            for (int w2 = 0; w2 < 8; ++w2) pr += projp[w2];
            ema = 0.8 * ema + 0.2 * pr;
            pred[b * T + t] = (float)ema;
        }
        v = vn; z = zn;
    }
}

extern "C" void kernel_launch(void* const* d_in, const int* in_sizes, int n_in,
                              void* d_out, int out_size, void* d_ws, size_t ws_size,
                              hipStream_t stream) {
    const float* inputs = (const float*)d_in[0];
    const float* w_in   = (const float*)d_in[1];
    const float* w_rec  = (const float*)d_in[2];
    const float* w_out  = (const float*)d_in[3];
    const float* b_out  = (const float*)d_in[4];
    float* out = (float*)d_out;

    k_in_gemm<16><<<dim3(B * T / 16), dim3(512), 0, stream>>>(inputs, w_in, out);

    const size_t need = (size_t)(NR + 1) * NR * sizeof(float);
    if (ws_size >= need) {
        float* w_ws = (float*)d_ws;
        k_prep<<<dim3(NR + 1), dim3(512), 0, stream>>>(w_rec, w_ws);
        k_scan<<<dim3(B), dim3(1024), 0, stream>>>(w_ws, out);
        k_pred<<<dim3(B), dim3(512), 0, stream>>>(w_out, b_out, out);
    } else {
        k_scan_ref<<<dim3(B), dim3(512), 0, stream>>>(w_rec, w_out, b_out, out);
    }
}